// Round 10
// baseline (248.176 us; speedup 1.0000x reference)
//
#include <hip/hip_runtime.h>
#include <hip/hip_bf16.h>
#include <math.h>
#include <stdint.h>

#define N_NODES 40000
#define N_EDGES 640000
#define F_IN    512
#define F_OUT   32
#define HEADS   8
#define C_OUT   (HEADS * F_OUT)   // 256
#define NEG_SLOPE 0.2f
#define EPS_F   1e-16f
#define MAXDEG  64                // bucket stride; max in-degree of the fixed
                                  // Poisson(16) graph is ~45 (P(>=64) ~ 1e-12)

typedef __attribute__((ext_vector_type(8)))  short  short8;
typedef __attribute__((ext_vector_type(4)))  short  short4v;
typedef __attribute__((ext_vector_type(16))) float  float16v;

// truncating fp32 -> (hi,lo) bf16 split: hi+lo represents f to ~2^-17 rel
__device__ __forceinline__ void splitT(float f, unsigned short& hi, unsigned short& lo) {
    unsigned u = __float_as_uint(f);
    hi = (unsigned short)(u >> 16);
    float r = f - __uint_as_float(u & 0xFFFF0000u);
    lo = (unsigned short)(__float_as_uint(r) >> 16);
}

__device__ __forceinline__ unsigned short f2bf(float f) {
    unsigned u = __float_as_uint(f);
    return (unsigned short)((u + 0x7FFF + ((u >> 16) & 1)) >> 16);
}

// barrier that does NOT drain vmcnt: LDS visibility needs lgkmcnt(0) only.
// In-flight vmem loads target private VGPRs -> safe to ride across the
// barrier (verified: passed R8/R9). __syncthreads() would emit
// s_waitcnt vmcnt(0) and expose the full latency of just-issued prefetches.
#define BARRIER_NOVM() asm volatile("s_waitcnt lgkmcnt(0)\n\ts_barrier" ::: "memory")

// ---------------------------------------------------------------------------
// K0: fused pack_W + cursor zeroing (one launch, independent work).
// Blocks [0,512): pack W into per-lane B-fragment layout for
// mfma_f32_32x32x16_bf16.
// Bp[wc4(4)][ktg(32)][ni(2)][lane(64)][j(8)], value =
//   B[k = ktg*16 + (lane>>5)*8 + j][col = wc4*64 + ni*32 + (lane&31)]
// where B[k][col] = W[col>>5][k][col&31].
// Blocks [512,552): zero the 40000-entry scatter cursor (int4 stores).
// ---------------------------------------------------------------------------
__global__ __launch_bounds__(256) void pack_zero(const float* __restrict__ W,
                                                 unsigned short* __restrict__ Bp,
                                                 int* __restrict__ cursor) {
    if (blockIdx.x < 512) {
        int tid = blockIdx.x * 256 + threadIdx.x;   // 131072 total
        int j    = tid & 7;
        int L    = (tid >> 3) & 63;
        int ni   = (tid >> 9) & 1;
        int ktg  = (tid >> 10) & 31;
        int wc   = tid >> 15;                        // 0..3
        int k    = ktg * 16 + (L >> 5) * 8 + j;
        int col  = wc * 64 + ni * 32 + (L & 31);
        int hh = col >> 5, f = col & 31;
        Bp[tid] = f2bf(W[hh * (F_IN * F_OUT) + k * F_OUT + f]);
    } else {
        int i = (blockIdx.x - 512) * 256 + threadIdx.x;   // 0..10239
        if (i < N_NODES / 4)
            *(int4*)&cursor[i * 4] = (int4){0, 0, 0, 0};
    }
}

// ---------------------------------------------------------------------------
// K1: fused MFMA projection GEMM + trailing bucket scatter.
// Blocks [0,1250): GEMM; blocks [1250,2500): bucket scatter (trailing fills
// the GEMM drain tail — R8/R9 A/B established front-scatter costs ~25us).
// GEMM: 512 threads = 8 waves, one wave per head; tile 32 rows x 256 cols;
// BK=64; 2-term bf16 split, split accumulators; double-buffered LDS; one
// NOVM barrier per K-step.
// DEEPENED PIPELINE vs R9 (per-step issue order):
//   1. breg for step st+1 (L2)          -> 1 full step of cover (~350cy>200)
//   2. x tile st+3 (HBM)                -> converted tile now has 2 steps of
//      cover (~700cy) instead of 1 (~350cy vs ~900cy HBM latency in R9)
//   3. convert tile st+1 (waits only its own load; younger loads ride)
//   4. MFMA on tile st (breg already resident from step st-1)
//   5. BARRIER_NOVM (drains LDS only; all vmem prefetches ride)
// In-order vmcnt: every wait targets a load OLDER than all riding prefetches.
// Epilogue: h16 stores + fused fp32-exact attention scores (head = wc).
// ---------------------------------------------------------------------------
#define AS 66   // k-stride in shorts: 64 + 2 pad (33 banks, odd -> bijection)
#define GEMM_BLOCKS 1250
#define SCAT_BLOCKS 1250

__global__ __launch_bounds__(512, 4) void gemm_scatter(const float* __restrict__ x,
                                                       const unsigned short* __restrict__ Bp,
                                                       const float* __restrict__ a_src,
                                                       const float* __restrict__ a_dst,
                                                       unsigned short* __restrict__ h16,
                                                       float* __restrict__ s_src,
                                                       float* __restrict__ s_dst,
                                                       const int* __restrict__ src,
                                                       const int* __restrict__ dst,
                                                       int* __restrict__ cursor,
                                                       int* __restrict__ src_buf) {
    if (blockIdx.x >= GEMM_BLOCKS) {
        int e = (blockIdx.x - GEMM_BLOCKS) * 512 + threadIdx.x;
        int s = src[e], d = dst[e];
        int pos = atomicAdd(&cursor[d], 1);
        if (pos < MAXDEG) src_buf[d * MAXDEG + pos] = s;
        return;
    }

    __shared__ unsigned short As_hi[2][32 * AS];
    __shared__ unsigned short As_lo[2][32 * AS];

    const int t = threadIdx.x;
    const int wc = t >> 6, L = t & 63;             // wave = head 0..7
    const int r31 = L & 31, half = L >> 5;
    const int n0 = blockIdx.x * 32;

    float16v accH, accL;
#pragma unroll
    for (int r = 0; r < 16; ++r) { accH[r] = 0.f; accL[r] = 0.f; }

    // staging: each thread loads ONE float4 (32 rows x 64 k per step)
    const int kcol = (t & 15) * 4;
    const int rbase = t >> 4;        // 0..31
    const float* xp = &x[(size_t)(n0 + rbase) * F_IN + kcol];

    // B fragment base for this wave: wc4 = wc>>1, ni = wc&1
    const unsigned short* bp =
        &Bp[((((size_t)(wc >> 1) * 32) * 2 + (wc & 1)) * 64 + L) * 8];
    // per global k-step ktg: offset ktg*1024 shorts

    // convert a staged float4 -> LDS buffer b
#define CONVW(b, s0) do {                                                      \
        unsigned short h0,h1,h2,h3,l0,l1,l2,l3;                                \
        splitT((s0).x,h0,l0); splitT((s0).y,h1,l1);                            \
        splitT((s0).z,h2,l2); splitT((s0).w,h3,l3);                            \
        int off_ = rbase*AS + kcol;                                            \
        *(short4v*)&As_hi[b][off_] =                                           \
            (short4v){(short)h0,(short)h1,(short)h2,(short)h3};                \
        *(short4v*)&As_lo[b][off_] =                                           \
            (short4v){(short)l0,(short)l1,(short)l2,(short)l3};                \
    } while (0)

    // prologue issue order: t0, breg(0), t1, t2 — convert waits only t0
    // (breg0/t1/t2 younger -> ride); MFMA@st0 waits breg0 (t1/t2 ride).
    float4 stgA = *(const float4*)(xp);          // tile 0
    short8 breg[4];
#pragma unroll
    for (int kt = 0; kt < 4; ++kt)
        breg[kt] = *(const short8*)(bp + (size_t)kt * 1024);
    float4 stgB = *(const float4*)(xp + 64);     // tile 1
    float4 stgC = *(const float4*)(xp + 128);    // tile 2
    CONVW(0, stgA);
    BARRIER_NOVM();                              // LDS[0] visible

#pragma unroll
    for (int st = 0; st < 8; ++st) {
        const int cur = st & 1, nxt = cur ^ 1;

        // ---- 1. prefetch B fragments for step st+1 (L2)
        short8 bregN[4];
        if (st < 7) {
#pragma unroll
            for (int kt = 0; kt < 4; ++kt)
                bregN[kt] = *(const short8*)(bp + (size_t)((st + 1) * 4 + kt) * 1024);
        }

        // ---- 2. issue HBM prefetch of tile st+3 (youngest outstanding)
        float4 stgD = stgC;
        if (st < 5) stgD = *(const float4*)(xp + (st + 3) * 64);

        // ---- 3. convert + LDS-write tile st+1 (issued 2 steps ago)
        if (st < 7) CONVW(nxt, stgB);

        // ---- 4. MFMA on tile st from LDS[cur]; breg resident since st-1
#pragma unroll
        for (int kt = 0; kt < 4; ++kt) {
            int off = r31 * AS + kt * 16 + half * 8;
            short8 ah = *(const short8*)&As_hi[cur][off];
            short8 al = *(const short8*)&As_lo[cur][off];
            accH = __builtin_amdgcn_mfma_f32_32x32x16_bf16(ah, breg[kt], accH, 0, 0, 0);
            accL = __builtin_amdgcn_mfma_f32_32x32x16_bf16(al, breg[kt], accL, 0, 0, 0);
        }

        // ---- 5. barrier (LDS only; vmem prefetches ride)
        if (st < 7) BARRIER_NOVM();

        // rotate pipeline registers (free renames under full unroll)
        stgB = stgC; stgC = stgD;
#pragma unroll
        for (int kt = 0; kt < 4; ++kt) breg[kt] = bregN[kt];
    }
#undef CONVW

    // ---- combine the two term-chains ----
#pragma unroll
    for (int r = 0; r < 16; ++r) accH[r] += accL[r];

    // ---- epilogue 1: h16 stores ----
    // C/D layout (32x32): col = lane&31, row = (reg&3) + 8*(reg>>2) + 4*half
    const int colb = wc * 32 + r31;
#pragma unroll
    for (int r = 0; r < 16; ++r) {
        int row = n0 + (r & 3) + 8 * (r >> 2) + 4 * half;
        h16[(size_t)row * C_OUT + colb] = f2bf(accH[r]);
    }

    // ---- epilogue 2: fused attention scores (fp32-exact); head = wc ----
    {
        float af = a_src[wc * 32 + r31];
        float df = a_dst[wc * 32 + r31];
#pragma unroll
        for (int r = 0; r < 16; ++r) {
            float v = accH[r];
            float vs = v * af;
            float vd = v * df;
#pragma unroll
            for (int m = 1; m < 32; m <<= 1) {
                vs += __shfl_xor(vs, m, 64);
                vd += __shfl_xor(vd, m, 64);
            }
            if (r31 == 0) {
                int row = n0 + (r & 3) + 8 * (r >> 2) + 4 * half;
                s_src[row * 8 + wc] = vs;
                s_dst[row * 8 + wc] = vd;
            }
        }
    }
}

// ---------------------------------------------------------------------------
// K6: aggregation, restructured for latency hiding:
// - ONE src_buf load per NODE (lane i holds edge i's id; sanitized once by
//   lane<cnt) — ids redistributed via __shfl (DS pipe), removing 8 per-batch
//   memory loads and their latency from the critical path.
// - w-masking folded into wx (invalid edge lanes compute wx=0, and shfl
//   distributes the zeros) -> full and tail batches UNIFY; the duplicated
//   masked-tail body is deleted (~40% of the old VALU work).
// - A/B software pipeline: batch b+1's h16 + s_src gathers issue BEFORE
//   batch b's FMAs consume -> gather latency hides under math.
// - next node's sReg/cnt/sd prefetched one full node ahead.
// Persistent waves: 2048 blocks x 4 waves = 8192 waves, ~5 nodes each.
// ---------------------------------------------------------------------------
__global__ __launch_bounds__(256) void aggregate(const int* __restrict__ src_buf,
                                                 const unsigned short* __restrict__ h16,
                                                 const float* __restrict__ s_src,
                                                 const float* __restrict__ s_dst,
                                                 const int* __restrict__ cursor,
                                                 const float* __restrict__ bias,
                                                 float* __restrict__ out) {
    const int t = threadIdx.x;
    const int wave = t >> 6, lane = t & 63;
    const int wgid = blockIdx.x * 4 + wave;   // 0..8191
    const int ch0 = lane * 4;
    const int hh = lane >> 3;
    const int eL = lane & 7;                  // edge slot this lane exps
    const int gbase = lane & 56;              // head-group base lane

    auto bf2f = [](short v) { return __uint_as_float(((unsigned)(unsigned short)v) << 16); };
    const float4 b4 = *(const float4*)&bias[ch0];

    // prologue: first node's metadata
    int sRegP = src_buf[wgid * MAXDEG + lane];
    int cntP  = cursor[wgid];
    float sdP = s_dst[wgid * 8 + hh];

    for (int n = wgid; n < N_NODES; n += 8192) {
        // issue next node's loads first (ride under this node's work)
        const int nn = n + 8192;
        int sRegN = 0, cntN = 0; float sdN = 0.f;
        if (nn < N_NODES) {
            sRegN = src_buf[nn * MAXDEG + lane];
            cntN  = cursor[nn];
            sdN   = s_dst[nn * 8 + hh];
        }

        const int cnt = cntP;
        const float sd = sdP;
        const int sReg = (lane < cnt) ? sRegP : 0;   // sanitize garbage ids once

        float a0 = 0.f, a1 = 0.f, a2 = 0.f, a3 = 0.f, den = 0.f;
        const int nb = (cnt + 7) >> 3;

        short4v vA[8], vB[8];
        float scA = 0.f, scB = 0.f;
        int vldA = 0, vldB = 0;

        // ids via shfl (no memory); gathers issued here, consumed in CONS_
#define PREF_(V, SC, VLD, b) do {                                              \
        _Pragma("unroll")                                                      \
        for (int u = 0; u < 8; ++u) {                                          \
            int id_ = __shfl(sReg, (b) * 8 + u, 64);                           \
            V[u] = *(const short4v*)&h16[(size_t)id_ * C_OUT + ch0];           \
        }                                                                      \
        int own_ = __shfl(sReg, (b) * 8 + eL, 64);                             \
        SC = s_src[own_ * 8 + hh];                                             \
        VLD = ((b) * 8 + eL) < cnt;                                            \
    } while (0)

#define CONS_(V, SC, VLD) do {                                                 \
        float e_ = SC + sd;                                                    \
        e_ = e_ >= 0.f ? e_ : NEG_SLOPE * e_;                                  \
        float wx_ = VLD ? __expf(e_) : 0.f;                                    \
        _Pragma("unroll")                                                      \
        for (int u = 0; u < 8; ++u) {                                          \
            float w_ = __shfl(wx_, gbase | u, 64);                             \
            a0 += w_ * bf2f(V[u][0]);                                          \
            a1 += w_ * bf2f(V[u][1]);                                          \
            a2 += w_ * bf2f(V[u][2]);                                          \
            a3 += w_ * bf2f(V[u][3]);                                          \
            den += w_;                                                         \
        }                                                                      \
    } while (0)

        if (nb > 0) {
            PREF_(vA, scA, vldA, 0);
            int b = 0;
            while (true) {
                if (b + 1 < nb) PREF_(vB, scB, vldB, b + 1);
                CONS_(vA, scA, vldA);
                if (++b >= nb) break;
                if (b + 1 < nb) PREF_(vA, scA, vldA, b + 1);
                CONS_(vB, scB, vldB);
                if (++b >= nb) break;
            }
        }
#undef PREF_
#undef CONS_

        float inv = 1.0f / (den + EPS_F);
        float4 o;
        o.x = a0 * inv + b4.x;
        o.y = a1 * inv + b4.y;
        o.z = a2 * inv + b4.z;
        o.w = a3 * inv + b4.w;
        *(float4*)&out[(size_t)n * C_OUT + ch0] = o;

        sRegP = sRegN; cntP = cntN; sdP = sdN;
    }
}

// ---------------------------------------------------------------------------
extern "C" void kernel_launch(void* const* d_in, const int* in_sizes, int n_in,
                              void* d_out, int out_size, void* d_ws, size_t ws_size,
                              hipStream_t stream) {
    const float* x     = (const float*)d_in[0];
    const int*   eidx  = (const int*)d_in[1];
    const float* W     = (const float*)d_in[2];
    const float* a_src = (const float*)d_in[3];
    const float* a_dst = (const float*)d_in[4];
    const float* bias  = (const float*)d_in[5];
    float* out = (float*)d_out;

    const int* src = eidx;
    const int* dst = eidx + N_EDGES;

    char* p = (char*)d_ws;
    auto carve = [&](size_t bytes) {
        char* r = p;
        p += (bytes + 255) & ~(size_t)255;
        return r;
    };
    unsigned short* h16 = (unsigned short*)carve((size_t)N_NODES * C_OUT * 2);     // 20.48 MB
    float* s_src      = (float*)carve((size_t)N_NODES * HEADS * 4);                // 1.28 MB
    float* s_dst      = (float*)carve((size_t)N_NODES * HEADS * 4);                // 1.28 MB
    int*   src_buf    = (int*)carve((size_t)N_NODES * MAXDEG * 4);                 // 10.24 MB
    int*   cursor     = (int*)carve((size_t)N_NODES * 4);                          // 0.16 MB
    unsigned short* Bp = (unsigned short*)carve((size_t)131072 * 2);               // 0.26 MB

    pack_zero<<<552, 256, 0, stream>>>(W, Bp, cursor);
    gemm_scatter<<<GEMM_BLOCKS + SCAT_BLOCKS, 512, 0, stream>>>(
        x, Bp, a_src, a_dst, h16, s_src, s_dst, src, dst, cursor, src_buf);
    aggregate<<<2048, 256, 0, stream>>>(src_buf, h16, s_src, s_dst,
                                        cursor, bias, out);
}

// Round 11
// 240.501 us; speedup vs baseline: 1.0319x; 1.0319x over previous
//
#include <hip/hip_runtime.h>
#include <hip/hip_bf16.h>
#include <math.h>
#include <stdint.h>

#define N_NODES 40000
#define N_EDGES 640000
#define F_IN    512
#define F_OUT   32
#define HEADS   8
#define C_OUT   (HEADS * F_OUT)   // 256
#define NEG_SLOPE 0.2f
#define EPS_F   1e-16f
#define MAXDEG  64                // bucket stride; max in-degree of the fixed
                                  // Poisson(16) graph is ~45 (P(>=64) ~ 1e-12)

typedef __attribute__((ext_vector_type(8)))  short  short8;
typedef __attribute__((ext_vector_type(4)))  short  short4v;
typedef __attribute__((ext_vector_type(16))) float  float16v;

// truncating fp32 -> (hi,lo) bf16 split: hi+lo represents f to ~2^-17 rel
__device__ __forceinline__ void splitT(float f, unsigned short& hi, unsigned short& lo) {
    unsigned u = __float_as_uint(f);
    hi = (unsigned short)(u >> 16);
    float r = f - __uint_as_float(u & 0xFFFF0000u);
    lo = (unsigned short)(__float_as_uint(r) >> 16);
}

__device__ __forceinline__ unsigned short f2bf(float f) {
    unsigned u = __float_as_uint(f);
    return (unsigned short)((u + 0x7FFF + ((u >> 16) & 1)) >> 16);
}

// barrier that does NOT drain vmcnt: LDS visibility needs lgkmcnt(0) only.
// In-flight vmem loads target private VGPRs -> safe to ride across the
// barrier (verified: R8/R9/R10 all pass). __syncthreads() would emit
// s_waitcnt vmcnt(0) and expose the full latency of just-issued prefetches.
#define BARRIER_NOVM() asm volatile("s_waitcnt lgkmcnt(0)\n\ts_barrier" ::: "memory")

// ---------------------------------------------------------------------------
// K0: fused pack_W + cursor zeroing (one launch, independent work).
// Blocks [0,512): pack W into per-lane B-fragment layout for
// mfma_f32_32x32x16_bf16.
// Bp[wc4(4)][ktg(32)][ni(2)][lane(64)][j(8)], value =
//   B[k = ktg*16 + (lane>>5)*8 + j][col = wc4*64 + ni*32 + (lane&31)]
// where B[k][col] = W[col>>5][k][col&31].
// Blocks [512,552): zero the 40000-entry scatter cursor (int4 stores).
// ---------------------------------------------------------------------------
__global__ __launch_bounds__(256) void pack_zero(const float* __restrict__ W,
                                                 unsigned short* __restrict__ Bp,
                                                 int* __restrict__ cursor) {
    if (blockIdx.x < 512) {
        int tid = blockIdx.x * 256 + threadIdx.x;   // 131072 total
        int j    = tid & 7;
        int L    = (tid >> 3) & 63;
        int ni   = (tid >> 9) & 1;
        int ktg  = (tid >> 10) & 31;
        int wc   = tid >> 15;                        // 0..3
        int k    = ktg * 16 + (L >> 5) * 8 + j;
        int col  = wc * 64 + ni * 32 + (L & 31);
        int hh = col >> 5, f = col & 31;
        Bp[tid] = f2bf(W[hh * (F_IN * F_OUT) + k * F_OUT + f]);
    } else {
        int i = (blockIdx.x - 512) * 256 + threadIdx.x;   // 0..10239
        if (i < N_NODES / 4)
            *(int4*)&cursor[i * 4] = (int4){0, 0, 0, 0};
    }
}

// ---------------------------------------------------------------------------
// K1: fused MFMA projection GEMM + trailing bucket scatter.
// Blocks [0,1250): GEMM; blocks [1250,2500): bucket scatter (trailing fills
// the GEMM drain tail — R8/R9 A/B established front-scatter costs ~25us).
// GEMM: 512 threads = 8 waves, one wave per head; tile 32 rows x 256 cols.
// BK=128 (was 64): 4 K-steps instead of 8 — HALVES the per-step sync cost
// (barrier reconvergence, breg L2-latency exposure, convert-wait exposure),
// which R6 (occupancy x2 = no change) and R10 (deeper prefetch = regression)
// isolated as the residual GEMM cost. Per step: 16 MFMA, 16 ds_read_b128,
// 2-float4 stage. LDS 2 x 16.6 KB, still 4 blocks/CU capacity.
// R9's proven pipeline (regressed R10 deepening reverted): per step
//   {breg (L2) -> HBM tile st+2 -> convert tile st+1 -> MFMA st -> NOVM}.
// In-order vmcnt: every wait targets a load older than all riding prefetches.
// 2-term bf16 split, split accumulators; LDS stride 130 shorts = 65 dwords
// (odd -> conflict-free row bijection, same property as the measured AS=66).
// Epilogue: h16 stores + fused fp32-exact attention scores (head = wc).
// ---------------------------------------------------------------------------
#define AS2 130  // k-stride in shorts: 128 + 2 pad (65 dwords, odd -> bijection)
#define GEMM_BLOCKS 1250
#define SCAT_BLOCKS 1250

__global__ __launch_bounds__(512, 4) void gemm_scatter(const float* __restrict__ x,
                                                       const unsigned short* __restrict__ Bp,
                                                       const float* __restrict__ a_src,
                                                       const float* __restrict__ a_dst,
                                                       unsigned short* __restrict__ h16,
                                                       float* __restrict__ s_src,
                                                       float* __restrict__ s_dst,
                                                       const int* __restrict__ src,
                                                       const int* __restrict__ dst,
                                                       int* __restrict__ cursor,
                                                       int* __restrict__ src_buf) {
    if (blockIdx.x >= GEMM_BLOCKS) {
        int e = (blockIdx.x - GEMM_BLOCKS) * 512 + threadIdx.x;
        int s = src[e], d = dst[e];
        int pos = atomicAdd(&cursor[d], 1);
        if (pos < MAXDEG) src_buf[d * MAXDEG + pos] = s;
        return;
    }

    __shared__ unsigned short As_hi[2][32 * AS2];
    __shared__ unsigned short As_lo[2][32 * AS2];

    const int t = threadIdx.x;
    const int wc = t >> 6, L = t & 63;             // wave = head 0..7
    const int r31 = L & 31, half = L >> 5;
    const int n0 = blockIdx.x * 32;

    float16v accH, accL;
#pragma unroll
    for (int r = 0; r < 16; ++r) { accH[r] = 0.f; accL[r] = 0.f; }

    // staging: each thread loads TWO float4 (32 rows x 128 k per step)
    const int kcol = (t & 15) * 4;
    const int rbase = t >> 4;        // 0..31
    const float* xp = &x[(size_t)(n0 + rbase) * F_IN + kcol];

    // B fragment base for this wave: wc4 = wc>>1, ni = wc&1
    const unsigned short* bp =
        &Bp[((((size_t)(wc >> 1) * 32) * 2 + (wc & 1)) * 64 + L) * 8];
    // per global k-step ktg (0..31): offset ktg*1024 shorts

    // convert a staged tile (two float4: k-halves 0 and 64) -> LDS buffer b
#define CONVW2(b, s0, s1) do {                                                 \
        unsigned short h0,h1,h2,h3,l0,l1,l2,l3;                                \
        int off_ = rbase*AS2 + kcol;                                           \
        splitT((s0).x,h0,l0); splitT((s0).y,h1,l1);                            \
        splitT((s0).z,h2,l2); splitT((s0).w,h3,l3);                            \
        *(short4v*)&As_hi[b][off_] =                                           \
            (short4v){(short)h0,(short)h1,(short)h2,(short)h3};                \
        *(short4v*)&As_lo[b][off_] =                                           \
            (short4v){(short)l0,(short)l1,(short)l2,(short)l3};                \
        splitT((s1).x,h0,l0); splitT((s1).y,h1,l1);                            \
        splitT((s1).z,h2,l2); splitT((s1).w,h3,l3);                            \
        *(short4v*)&As_hi[b][off_ + 64] =                                      \
            (short4v){(short)h0,(short)h1,(short)h2,(short)h3};                \
        *(short4v*)&As_lo[b][off_ + 64] =                                      \
            (short4v){(short)l0,(short)l1,(short)l2,(short)l3};                \
    } while (0)

    // prologue issue order: tile0 (2 loads), tile1 (2 loads) — convert waits
    // only tile0 (tile1 younger -> rides into the loop).
    float4 stgA0 = *(const float4*)(xp);
    float4 stgA1 = *(const float4*)(xp + 64);
    float4 stgB0 = *(const float4*)(xp + 128);
    float4 stgB1 = *(const float4*)(xp + 192);
    CONVW2(0, stgA0, stgA1);
    BARRIER_NOVM();                              // LDS[0] visible; tile-1 rides

#pragma unroll
    for (int st = 0; st < 4; ++st) {
        const int cur = st & 1, nxt = cur ^ 1;

        // ---- B fragments (L2); their wait leaves the HBM prefetch in flight
        short8 breg[8];
#pragma unroll
        for (int kt = 0; kt < 8; ++kt)
            breg[kt] = *(const short8*)(bp + (size_t)(st * 8 + kt) * 1024);

        // ---- issue HBM prefetch of tile st+2 (youngest outstanding)
        float4 stgC0 = stgB0, stgC1 = stgB1;
        if (st < 2) {
            stgC0 = *(const float4*)(xp + (st + 2) * 128);
            stgC1 = *(const float4*)(xp + (st + 2) * 128 + 64);
        }

        // ---- convert + LDS-write tile st+1 (issued one step ago)
        if (st < 3) CONVW2(nxt, stgB0, stgB1);

        // ---- MFMA on tile st from LDS[cur]; two independent term-chains ----
#pragma unroll
        for (int kt = 0; kt < 8; ++kt) {
            int off = r31 * AS2 + kt * 16 + half * 8;
            short8 ah = *(const short8*)&As_hi[cur][off];
            short8 al = *(const short8*)&As_lo[cur][off];
            accH = __builtin_amdgcn_mfma_f32_32x32x16_bf16(ah, breg[kt], accH, 0, 0, 0);
            accL = __builtin_amdgcn_mfma_f32_32x32x16_bf16(al, breg[kt], accL, 0, 0, 0);
        }

        // ---- barrier (LDS only; vmem prefetches ride)
        if (st < 3) BARRIER_NOVM();

        stgB0 = stgC0; stgB1 = stgC1;
    }
#undef CONVW2

    // ---- combine the two term-chains ----
#pragma unroll
    for (int r = 0; r < 16; ++r) accH[r] += accL[r];

    // ---- epilogue 1: h16 stores ----
    // C/D layout (32x32): col = lane&31, row = (reg&3) + 8*(reg>>2) + 4*half
    const int colb = wc * 32 + r31;
#pragma unroll
    for (int r = 0; r < 16; ++r) {
        int row = n0 + (r & 3) + 8 * (r >> 2) + 4 * half;
        h16[(size_t)row * C_OUT + colb] = f2bf(accH[r]);
    }

    // ---- epilogue 2: fused attention scores (fp32-exact); head = wc ----
    {
        float af = a_src[wc * 32 + r31];
        float df = a_dst[wc * 32 + r31];
#pragma unroll
        for (int r = 0; r < 16; ++r) {
            float v = accH[r];
            float vs = v * af;
            float vd = v * df;
#pragma unroll
            for (int m = 1; m < 32; m <<= 1) {
                vs += __shfl_xor(vs, m, 64);
                vd += __shfl_xor(vd, m, 64);
            }
            if (r31 == 0) {
                int row = n0 + (r & 3) + 8 * (r >> 2) + 4 * half;
                s_src[row * 8 + wc] = vs;
                s_dst[row * 8 + wc] = vd;
            }
        }
    }
}

// ---------------------------------------------------------------------------
// K6: aggregation (R10 structure — neutral-to-better vs R9 per decomposition).
// - ONE src_buf load per NODE (lane i holds edge i's id; sanitized once by
//   lane<cnt); ids redistributed via __shfl (DS pipe).
// - w-masking folded into wx -> full and tail batches unify.
// - A/B software pipeline: batch b+1's h16 + s_src gathers issue BEFORE
//   batch b's FMAs consume.
// - next node's sReg/cnt/sd prefetched one full node ahead.
// Persistent waves: 2048 blocks x 4 waves = 8192 waves, ~5 nodes each.
// ---------------------------------------------------------------------------
__global__ __launch_bounds__(256) void aggregate(const int* __restrict__ src_buf,
                                                 const unsigned short* __restrict__ h16,
                                                 const float* __restrict__ s_src,
                                                 const float* __restrict__ s_dst,
                                                 const int* __restrict__ cursor,
                                                 const float* __restrict__ bias,
                                                 float* __restrict__ out) {
    const int t = threadIdx.x;
    const int wave = t >> 6, lane = t & 63;
    const int wgid = blockIdx.x * 4 + wave;   // 0..8191
    const int ch0 = lane * 4;
    const int hh = lane >> 3;
    const int eL = lane & 7;                  // edge slot this lane exps
    const int gbase = lane & 56;              // head-group base lane

    auto bf2f = [](short v) { return __uint_as_float(((unsigned)(unsigned short)v) << 16); };
    const float4 b4 = *(const float4*)&bias[ch0];

    // prologue: first node's metadata
    int sRegP = src_buf[wgid * MAXDEG + lane];
    int cntP  = cursor[wgid];
    float sdP = s_dst[wgid * 8 + hh];

    for (int n = wgid; n < N_NODES; n += 8192) {
        // issue next node's loads first (ride under this node's work)
        const int nn = n + 8192;
        int sRegN = 0, cntN = 0; float sdN = 0.f;
        if (nn < N_NODES) {
            sRegN = src_buf[nn * MAXDEG + lane];
            cntN  = cursor[nn];
            sdN   = s_dst[nn * 8 + hh];
        }

        const int cnt = cntP;
        const float sd = sdP;
        const int sReg = (lane < cnt) ? sRegP : 0;   // sanitize garbage ids once

        float a0 = 0.f, a1 = 0.f, a2 = 0.f, a3 = 0.f, den = 0.f;
        const int nb = (cnt + 7) >> 3;

        short4v vA[8], vB[8];
        float scA = 0.f, scB = 0.f;
        int vldA = 0, vldB = 0;

        // ids via shfl (no memory); gathers issued here, consumed in CONS_
#define PREF_(V, SC, VLD, b) do {                                              \
        _Pragma("unroll")                                                      \
        for (int u = 0; u < 8; ++u) {                                          \
            int id_ = __shfl(sReg, (b) * 8 + u, 64);                           \
            V[u] = *(const short4v*)&h16[(size_t)id_ * C_OUT + ch0];           \
        }                                                                      \
        int own_ = __shfl(sReg, (b) * 8 + eL, 64);                             \
        SC = s_src[own_ * 8 + hh];                                             \
        VLD = ((b) * 8 + eL) < cnt;                                            \
    } while (0)

#define CONS_(V, SC, VLD) do {                                                 \
        float e_ = SC + sd;                                                    \
        e_ = e_ >= 0.f ? e_ : NEG_SLOPE * e_;                                  \
        float wx_ = VLD ? __expf(e_) : 0.f;                                    \
        _Pragma("unroll")                                                      \
        for (int u = 0; u < 8; ++u) {                                          \
            float w_ = __shfl(wx_, gbase | u, 64);                             \
            a0 += w_ * bf2f(V[u][0]);                                          \
            a1 += w_ * bf2f(V[u][1]);                                          \
            a2 += w_ * bf2f(V[u][2]);                                          \
            a3 += w_ * bf2f(V[u][3]);                                          \
            den += w_;                                                         \
        }                                                                      \
    } while (0)

        if (nb > 0) {
            PREF_(vA, scA, vldA, 0);
            int b = 0;
            while (true) {
                if (b + 1 < nb) PREF_(vB, scB, vldB, b + 1);
                CONS_(vA, scA, vldA);
                if (++b >= nb) break;
                if (b + 1 < nb) PREF_(vA, scA, vldA, b + 1);
                CONS_(vB, scB, vldB);
                if (++b >= nb) break;
            }
        }
#undef PREF_
#undef CONS_

        float inv = 1.0f / (den + EPS_F);
        float4 o;
        o.x = a0 * inv + b4.x;
        o.y = a1 * inv + b4.y;
        o.z = a2 * inv + b4.z;
        o.w = a3 * inv + b4.w;
        *(float4*)&out[(size_t)n * C_OUT + ch0] = o;

        sRegP = sRegN; cntP = cntN; sdP = sdN;
    }
}

// ---------------------------------------------------------------------------
extern "C" void kernel_launch(void* const* d_in, const int* in_sizes, int n_in,
                              void* d_out, int out_size, void* d_ws, size_t ws_size,
                              hipStream_t stream) {
    const float* x     = (const float*)d_in[0];
    const int*   eidx  = (const int*)d_in[1];
    const float* W     = (const float*)d_in[2];
    const float* a_src = (const float*)d_in[3];
    const float* a_dst = (const float*)d_in[4];
    const float* bias  = (const float*)d_in[5];
    float* out = (float*)d_out;

    const int* src = eidx;
    const int* dst = eidx + N_EDGES;

    char* p = (char*)d_ws;
    auto carve = [&](size_t bytes) {
        char* r = p;
        p += (bytes + 255) & ~(size_t)255;
        return r;
    };
    unsigned short* h16 = (unsigned short*)carve((size_t)N_NODES * C_OUT * 2);     // 20.48 MB
    float* s_src      = (float*)carve((size_t)N_NODES * HEADS * 4);                // 1.28 MB
    float* s_dst      = (float*)carve((size_t)N_NODES * HEADS * 4);                // 1.28 MB
    int*   src_buf    = (int*)carve((size_t)N_NODES * MAXDEG * 4);                 // 10.24 MB
    int*   cursor     = (int*)carve((size_t)N_NODES * 4);                          // 0.16 MB
    unsigned short* Bp = (unsigned short*)carve((size_t)131072 * 2);               // 0.26 MB

    pack_zero<<<552, 256, 0, stream>>>(W, Bp, cursor);
    gemm_scatter<<<GEMM_BLOCKS + SCAT_BLOCKS, 512, 0, stream>>>(
        x, Bp, a_src, a_dst, h16, s_src, s_dst, src, dst, cursor, src_buf);
    aggregate<<<2048, 256, 0, stream>>>(src_buf, h16, s_src, s_dst,
                                        cursor, bias, out);
}